// Round 4
// baseline (3722.227 us; speedup 1.0000x reference)
//
#include <hip/hip_runtime.h>
#include <stdint.h>

// Problem constants (bidirectionalRNN: S=256, B=32, I=H=1024, L=2)
#define SEQ   256
#define BSZ   32
#define HD    1024
#define GD    4096          // 4*H
#define KD    1024
#define MROWS (SEQ*BSZ)     // 8192
#define PBLK  128           // persistent grid: 128 blocks, co-resident (<=256 CUs)
#define PTHR  512           // 8 waves: 4 gate-tiles x 2 K-halves

typedef unsigned short u16;
typedef __attribute__((ext_vector_type(8))) __bf16 bf8_t;
typedef __attribute__((ext_vector_type(4))) float  f4_t;
typedef __attribute__((ext_vector_type(4))) unsigned int u4_t;

__device__ __forceinline__ u16 f2bf(float f) {
  unsigned u = __float_as_uint(f);
  u += 0x7fffu + ((u >> 16) & 1u);      // RNE
  return (u16)(u >> 16);
}
__device__ __forceinline__ float bf2f(u16 s) {
  return __uint_as_float(((unsigned)s) << 16);
}
__device__ __forceinline__ void async_copy16(const void* g, void* l) {
  __builtin_amdgcn_global_load_lds(
      (const __attribute__((address_space(1))) void*)g,
      (__attribute__((address_space(3))) void*)l, 16, 0, 0);
}
__device__ __forceinline__ float sigm(float x) { return 1.0f / (1.0f + __expf(-x)); }
__device__ __forceinline__ float tanh_f(float x) {
  float e = __expf(-2.0f * x);          // inf-safe: x<<0 -> e=inf -> -1
  return 2.0f / (1.0f + e) - 1.0f;
}

// ---------------- fp32 -> bf16 conversion (x4 vectorized) ----------------
__global__ void cvt_f32_bf16(const float* __restrict__ src, u16* __restrict__ dst, int n4) {
  int i = blockIdx.x * blockDim.x + threadIdx.x;
  if (i >= n4) return;
  float4 v = ((const float4*)src)[i];
  ushort4 o;
  o.x = f2bf(v.x); o.y = f2bf(v.y); o.z = f2bf(v.z); o.w = f2bf(v.w);
  ((ushort4*)dst)[i] = o;
}

// ------- w_hh reorder+convert: gate-interleaved block-owned row layout ----
__global__ void reorder_whh(const float* __restrict__ src, u16* __restrict__ dst, int d) {
  int r = blockIdx.x;                 // 0..8191
  int layer = r >> 12, row = r & 4095;
  int g = row >> 10, j = row & 1023;
  int jblk = j >> 4, jl = j & 15;
  size_t drow = ((size_t)(d * 2 + layer) * 64 + jblk) * 64 + g * 16 + jl;
  float4 v = ((const float4*)(src + (size_t)r * KD))[threadIdx.x];
  ushort4 o;
  o.x = f2bf(v.x); o.y = f2bf(v.y); o.z = f2bf(v.z); o.w = f2bf(v.w);
  ((ushort4*)(dst + drow * KD))[threadIdx.x] = o;
}

// ---------------- bf16 GEMM: C[M,N] = A[M,K] @ B[N,K]^T, C in bf16 -------
__global__ __launch_bounds__(256) void gemm_bt(
    const u16* __restrict__ A, const u16* __restrict__ B, u16* __restrict__ C,
    int M, int N, int K)
{
  __shared__ u16 lA[128 * 32];
  __shared__ u16 lB[128 * 32];
  const int tid  = threadIdx.x;
  const int wave = tid >> 6, lane = tid & 63;
  const int wr = (wave >> 1) * 64, wc = (wave & 1) * 64;
  const int m0 = blockIdx.x * 128, n0 = blockIdx.y * 128;

  f4_t acc[4][4] = {};

  const int r0 = tid >> 2,          kp0 = (tid & 3) * 8;
  const int r1 = (tid + 256) >> 2,  kp1 = (tid & 3) * 8;
  const u16* gA0 = A + (size_t)(m0 + r0) * K + kp0;
  const u16* gA1 = A + (size_t)(m0 + r1) * K + kp1;
  const u16* gB0 = B + (size_t)(n0 + r0) * K + kp0;
  const u16* gB1 = B + (size_t)(n0 + r1) * K + kp1;
  u16* lA0 = lA + wave * 512;          u16* lA1 = lA + 2048 + wave * 512;
  u16* lB0 = lB + wave * 512;          u16* lB1 = lB + 2048 + wave * 512;

  const int fr = lane & 15, fk = (lane >> 4) * 8;

  for (int k0 = 0; k0 < K; k0 += 32) {
    async_copy16(gA0 + k0, lA0);
    async_copy16(gA1 + k0, lA1);
    async_copy16(gB0 + k0, lB0);
    async_copy16(gB1 + k0, lB1);
    __syncthreads();
    bf8_t af[4], bf[4];
    #pragma unroll
    for (int i = 0; i < 4; i++) af[i] = *(const bf8_t*)&lA[(wr + i * 16 + fr) * 32 + fk];
    #pragma unroll
    for (int i = 0; i < 4; i++) bf[i] = *(const bf8_t*)&lB[(wc + i * 16 + fr) * 32 + fk];
    #pragma unroll
    for (int mi = 0; mi < 4; mi++)
      #pragma unroll
      for (int ni = 0; ni < 4; ni++)
        acc[mi][ni] = __builtin_amdgcn_mfma_f32_16x16x32_bf16(af[mi], bf[ni], acc[mi][ni], 0, 0, 0);
    __syncthreads();
  }
  const int er = (lane >> 4) * 4, ec = lane & 15;
  #pragma unroll
  for (int mi = 0; mi < 4; mi++)
    #pragma unroll
    for (int ni = 0; ni < 4; ni++)
      #pragma unroll
      for (int r = 0; r < 4; r++) {
        int m = m0 + wr + mi * 16 + er + r;
        int n = n0 + wc + ni * 16 + ec;
        C[(size_t)m * N + n] = f2bf(acc[mi][ni][r]);
      }
}

// -------- persistent weight-stationary recurrence (one launch per layer) --
// 128 blocks x 512 thr. Block: dir d = bid&1, jblk = bid>>1 -> 16 h-dims, all
// 4 gates. All 8 waves do MFMA (gate mt = wv>>1, K-half kh = wv&1). Waves 0-3
// additionally run the cell phase (batches [wv*8, wv*8+8)); waves 4-7 are the
// h-exchange consumers (poll + stage).
//
// h exchange protocol (race-free, replay-robust, NO lockstep):
//   producer (cell wave w of block jblk): sc1 h stores -> s_waitcnt vmcnt(0)
//     -> sc1 flag store flags[w*64+jblk] = t+1. (stores performed at MALL
//     before the flag is.)
//   consumer (wave 4+q): polls its 64 matching flags (one coalesced 64-lane
//     sc1 load + __all), then stages EXACTLY the batch rows produced by cell
//     wave q (rows [q*8,q*8+8)) via sc1 loads -> LDS. Flag<->data dependency
//     is exact; blocks may skew (trajectory slots are write-once), so fast
//     blocks pipeline ahead instead of lockstepping on stragglers.
// Syncs per step: syncA (lH staged) + syncBC (lAcc ready). lAcc is a separate
// 16KB region so staging never aliases it. Deadlock-free by induction: step-t
// flags are published unconditionally at the end of step t-1 by every
// co-resident block (128 blocks <= 256 CUs).
__global__ __launch_bounds__(PTHR) void lstm_persist(
    const u16* __restrict__ whh_r,  // [2d][2l][64 jblk][64 rows][1024] bf16
    const u16* __restrict__ xg,     // [2d][8192][4096] bf16
    u16*       __restrict__ htraj,  // [2d][8192][1024] bf16: slot tt = h(tt)
    float*     __restrict__ dout,
    unsigned*  __restrict__ flagsb, // zeroed; per-dir +d*512; idx w*64+jblk
    int layer)
{
  const int tid = threadIdx.x;
  const int lane = tid & 63;
  const int wv  = tid >> 6;
  const int mt = wv >> 1, kh = wv & 1;
  const int d = blockIdx.x & 1, jblk = blockIdx.x >> 1;
  const int j0 = jblk * 16;
  const int fr = lane & 15, quad = lane >> 4;
  unsigned* flags = flagsb + (size_t)d * 512;

  __builtin_amdgcn_fence(__ATOMIC_ACQUIRE, "agent");   // once: drop stale lines

  // 64 KB: h staging [32 rows(b)][128 chunks(16B)], phys chunk = c ^ (row&7)
  __shared__ __align__(16) uint32_t lH[32 * 512];
  // 16 KB separate gate-partial exchange buffer [4 mt][2 kh][32 b][16 j]
  __shared__ __align__(16) float lAcc[4096];

  // ---- one-time weight fragment load, pinned in VGPRs ----
  u4_t wreg[16];
  {
    const u16* wp = whh_r
        + ((size_t)(((d * 2 + layer) * 64 + jblk) * 64 + mt * 16 + fr)) * KD
        + kh * 512 + quad * 8;
    #pragma unroll
    for (int ks = 0; ks < 16; ks++) wreg[ks] = *(const u4_t*)(wp + ks * 32);
    #pragma unroll
    for (int ks = 0; ks < 16; ks++) asm volatile("" : "+v"(wreg[ks]));  // stop load sinking
  }

  const int b_ = tid >> 3, jp = tid & 7;   // cell phase: tid<256 -> (batch, j-pair)
  float cr0 = 0.0f, cr1 = 0.0f;

  // xg for step 0 (later steps prefetch during the cell phase)
  uint32_t xv[4] = {};
  if (tid < 256) {
    const int tt0 = d ? (SEQ - 1) : 0;
    const uint32_t* xgp = (const uint32_t*)(xg
        + ((size_t)d * MROWS + (size_t)tt0 * BSZ + b_) * GD + j0) + jp;
    #pragma unroll
    for (int g = 0; g < 4; g++) xv[g] = xgp[g * 512];
  }

  for (int t = 0; t < SEQ; t++) {
    const int tt = d ? (SEQ - 1 - t) : t;

    if (t > 0) {
      if (wv >= 4) {
        const int q = wv - 4;               // matching producer wave
        // ---- poll: lane l watches flags[q*64 + l] (block l, wave q) ----
        {
          long spins = 0;
          for (;;) {
            unsigned v = __hip_atomic_load(&flags[q * 64 + lane],
                __ATOMIC_RELAXED, __HIP_MEMORY_SCOPE_AGENT);
            if (__all((int)(v >= (unsigned)t))) break;
            if (++spins > (1L << 24)) break;   // safety escape (deadlock only)
          }
        }
        asm volatile("" ::: "memory");      // keep stage loads below the poll
        // ---- stage rows [q*8, q*8+8) of h(prev): sc1 8B loads -> LDS ----
        // Two halves of 8 chunks to cap load-result liveness (VGPR pressure).
        const int ttp = d ? (tt + 1) : (tt - 1);
        const unsigned long long* hs8 = (const unsigned long long*)(htraj
            + ((size_t)d * MROWS + (size_t)ttp * BSZ) * HD);
        #pragma unroll
        for (int hf = 0; hf < 2; hf++) {
          unsigned long long hv2[16];
          #pragma unroll
          for (int k = 0; k < 8; k++) {
            int kk  = hf * 8 + k;
            int row = q * 8 + (kk >> 1);
            int c   = (kk & 1) * 64 + lane;
            size_t ci = ((size_t)row * 128 + c) * 2;
            hv2[2 * k]     = __hip_atomic_load(hs8 + ci,     __ATOMIC_RELAXED, __HIP_MEMORY_SCOPE_AGENT);
            hv2[2 * k + 1] = __hip_atomic_load(hs8 + ci + 1, __ATOMIC_RELAXED, __HIP_MEMORY_SCOPE_AGENT);
          }
          #pragma unroll
          for (int k = 0; k < 8; k++) {
            int kk  = hf * 8 + k;
            int row = q * 8 + (kk >> 1);
            int c   = (kk & 1) * 64 + lane;
            int pc  = c ^ (row & 7);
            uint2 lo = __builtin_bit_cast(uint2, hv2[2 * k]);
            uint2 hi = __builtin_bit_cast(uint2, hv2[2 * k + 1]);
            u4_t v; v.x = lo.x; v.y = lo.y; v.z = hi.x; v.w = hi.y;
            *(u4_t*)&lH[row * 512 + pc * 4] = v;
          }
        }
      }
      __syncthreads();                      // A: lH fully staged

      // ---- recurrent MFMA: gate mt, K-half kh (all 8 waves) ----
      f4_t acc0 = {}, acc1 = {};
      #pragma unroll
      for (int ks = 0; ks < 16; ks++) {
        int cbase = ((kh * 64 + ks * 4 + quad) ^ (fr & 7)) << 2;  // (fr+16)&7==fr&7
        bf8_t a0 = *(const bf8_t*)&lH[fr * 512 + cbase];          // batches 0-15
        bf8_t a1 = *(const bf8_t*)&lH[(fr + 16) * 512 + cbase];   // batches 16-31
        bf8_t wb = __builtin_bit_cast(bf8_t, wreg[ks]);
        acc0 = __builtin_amdgcn_mfma_f32_16x16x32_bf16(a0, wb, acc0, 0, 0, 0);
        acc1 = __builtin_amdgcn_mfma_f32_16x16x32_bf16(a1, wb, acc1, 0, 0, 0);
      }
      // D layout: col=lane&15 (j), row=(lane>>4)*4+r (batch)
      #pragma unroll
      for (int r = 0; r < 4; r++) {
        lAcc[((mt * 2 + kh) * 32 + quad * 4 + r) * 16 + fr]      = acc0[r];
        lAcc[((mt * 2 + kh) * 32 + 16 + quad * 4 + r) * 16 + fr] = acc1[r];
      }
    }
    __syncthreads();                        // BC: lAcc ready (uniform at t=0 too)

    // ---- cell update: 256 threads x 2 adjacent j each ----
    if (tid < 256) {
      float vg0[4], vg1[4];
      #pragma unroll
      for (int g = 0; g < 4; g++) {
        float s0 = 0.f, s1 = 0.f;
        if (t > 0) {
          float2 p0 = *(const float2*)&lAcc[((g * 2 + 0) * 32 + b_) * 16 + 2 * jp];
          float2 p1 = *(const float2*)&lAcc[((g * 2 + 1) * 32 + b_) * 16 + 2 * jp];
          s0 = p0.x + p1.x; s1 = p0.y + p1.y;
        }
        vg0[g] = s0 + bf2f((u16)(xv[g] & 0xffffu));
        vg1[g] = s1 + bf2f((u16)(xv[g] >> 16));
      }
      float i0 = sigm(vg0[0]), f0 = sigm(vg0[1]), g0 = tanh_f(vg0[2]), o0 = sigm(vg0[3]);
      float i1 = sigm(vg1[0]), f1 = sigm(vg1[1]), g1 = tanh_f(vg1[2]), o1 = sigm(vg1[3]);
      cr0 = f0 * cr0 + i0 * g0;
      cr1 = f1 * cr1 + i1 * g1;
      float hn0 = o0 * tanh_f(cr0), hn1 = o1 * tanh_f(cr1);
      uint32_t hnp = ((uint32_t)f2bf(hn1) << 16) | (uint32_t)f2bf(hn0);

      // trajectory store (device-coherent write-through, performed at MALL)
      size_t hq = (((size_t)d * MROWS + (size_t)tt * BSZ + b_) * HD + j0 + 2 * jp) >> 1;
      __hip_atomic_store((uint32_t*)htraj + hq, hnp, __ATOMIC_RELAXED, __HIP_MEMORY_SCOPE_AGENT);

      if (layer == 1) {
        float2 o2 = make_float2(hn0, hn1);
        *(float2*)&dout[((size_t)tt * BSZ + b_) * (2 * HD) + (size_t)d * HD + j0 + 2 * jp] = o2;
      }
      // h_last/c_last: fwd at final step; bwd at its FIRST step (torch quirk)
      if ((d == 0 && t == SEQ - 1) || (d == 1 && t == 0)) {
        size_t hoff = (size_t)MROWS * 2 * HD + ((size_t)layer * BSZ + b_) * (2 * HD)
                    + (size_t)d * HD + j0 + 2 * jp;
        dout[hoff] = hn0;  dout[hoff + 1] = hn1;
        dout[hoff + (size_t)2 * BSZ * 2 * HD]     = cr0;
        dout[hoff + (size_t)2 * BSZ * 2 * HD + 1] = cr1;
      }

      // ---- drain own stores to MALL, then signal this wave's flag ----
      asm volatile("s_waitcnt vmcnt(0)" ::: "memory");
      if (lane == 0)
        __hip_atomic_store(&flags[wv * 64 + jblk], (unsigned)(t + 1),
                           __ATOMIC_RELAXED, __HIP_MEMORY_SCOPE_AGENT);

      // ---- prefetch next step's xg (plain cached: replay-deterministic) ----
      if (t + 1 < SEQ) {
        const int ttn = d ? (SEQ - 2 - t) : (t + 1);
        const uint32_t* xgp = (const uint32_t*)(xg
            + ((size_t)d * MROWS + (size_t)ttn * BSZ + b_) * GD + j0) + jp;
        #pragma unroll
        for (int g = 0; g < 4; g++) xv[g] = xgp[g * 512];
      }
    }
  }
}

// -------------------------------------------------------------------------
extern "C" void kernel_launch(void* const* d_in, const int* in_sizes, int n_in,
                              void* d_out, int out_size, void* d_ws, size_t ws_size,
                              hipStream_t stream) {
  const float* x    = (const float*)d_in[0];
  const float* wihf = (const float*)d_in[1];
  const float* whhf = (const float*)d_in[2];
  const float* wihb = (const float*)d_in[3];
  const float* whhb = (const float*)d_in[4];
  float* out = (float*)d_out;

  const size_t NE = (size_t)MROWS * KD;   // 8.4M elems per [2,4096,1024] tensor
  char* ws = (char*)d_ws;
  u16*   xbf  = (u16*)ws;                                   // 16 MB
  u16*   wih  = (u16*)(ws + NE * 2);                        // 32 MB
  u16*   whhr = wih + 2 * NE;                               // reordered, 32 MB
  u16*   xg   = whhr + 2 * NE;                              // 128 MB
  u16*   h0   = xg + (size_t)2 * MROWS * GD;                // 32 MB (trajectory, both layers)
  unsigned* cnt = (unsigned*)(h0 + (size_t)2 * MROWS * HD); // flags: 2 layers x 2 dirs x 2 KB

  const int n4 = (int)(NE / 4);
  const int cg = n4 / 256;
  cvt_f32_bf16<<<cg, 256, 0, stream>>>(x,    xbf,      n4);
  cvt_f32_bf16<<<cg, 256, 0, stream>>>(wihf, wih,      n4);
  cvt_f32_bf16<<<cg, 256, 0, stream>>>(wihb, wih + NE, n4);
  reorder_whh<<<2 * GD, 256, 0, stream>>>(whhf, whhr, 0);
  reorder_whh<<<2 * GD, 256, 0, stream>>>(whhb, whhr, 1);

  hipMemsetAsync(cnt, 0, 4 * 512 * sizeof(unsigned), stream);

  dim3 gg(MROWS / 128, GD / 128);   // 64 x 32

  // layer 0: xg GEMMs, then persistent recurrence (h trajectory -> h0)
  for (int d = 0; d < 2; d++)
    gemm_bt<<<gg, 256, 0, stream>>>(xbf, wih + (size_t)(d * 2) * GD * KD,
                                    xg + (size_t)d * MROWS * GD, MROWS, GD, KD);
  lstm_persist<<<PBLK, PTHR, 0, stream>>>(whhr, xg, h0, out, cnt, 0);

  // layer 1: xg GEMMs read h0, then recurrence overwrites h0 as its trajectory
  for (int d = 0; d < 2; d++)
    gemm_bt<<<gg, 256, 0, stream>>>(h0 + (size_t)d * MROWS * HD,
                                    wih + (size_t)(d * 2 + 1) * GD * KD,
                                    xg + (size_t)d * MROWS * GD, MROWS, GD, KD);
  lstm_persist<<<PBLK, PTHR, 0, stream>>>(whhr, xg, h0, out, cnt + 1024, 1);
}

// Round 5
// 3026.977 us; speedup vs baseline: 1.2297x; 1.2297x over previous
//
#include <hip/hip_runtime.h>
#include <stdint.h>

// Problem constants (bidirectionalRNN: S=256, B=32, I=H=1024, L=2)
#define SEQ   256
#define BSZ   32
#define HD    1024
#define GD    4096          // 4*H
#define KD    1024
#define MROWS (SEQ*BSZ)     // 8192
#define PBLK  256           // fused persistent grid: 128 blocks/layer, 1 block/CU
#define PTHR  512           // 8 waves: 4 gate-tiles x 2 K-halves

typedef unsigned short u16;
typedef __attribute__((ext_vector_type(8))) __bf16 bf8_t;
typedef __attribute__((ext_vector_type(4))) float  f4_t;
typedef __attribute__((ext_vector_type(4))) unsigned int u4_t;

__device__ __forceinline__ u16 f2bf(float f) {
  unsigned u = __float_as_uint(f);
  u += 0x7fffu + ((u >> 16) & 1u);      // RNE
  return (u16)(u >> 16);
}
__device__ __forceinline__ float sigm(float x) { return 1.0f / (1.0f + __expf(-x)); }
__device__ __forceinline__ float tanh_f(float x) {
  float e = __expf(-2.0f * x);          // inf-safe: x<<0 -> e=inf -> -1
  return 2.0f / (1.0f + e) - 1.0f;
}

// ---------------- fp32 -> bf16 conversion (x4 vectorized) ----------------
__global__ void cvt_f32_bf16(const float* __restrict__ src, u16* __restrict__ dst, int n4) {
  int i = blockIdx.x * blockDim.x + threadIdx.x;
  if (i >= n4) return;
  float4 v = ((const float4*)src)[i];
  ushort4 o;
  o.x = f2bf(v.x); o.y = f2bf(v.y); o.z = f2bf(v.z); o.w = f2bf(v.w);
  ((ushort4*)dst)[i] = o;
}

// --- weight reorder+convert: gate-interleaved block-owned row layout ------
// src: [2 layers][4096][1024] f32 (one direction of w_ih or w_hh).
// dst row ((d*2+layer)*64 + jblk)*64 + g*16 + jl  <-  src row g*1024 + jblk*16 + jl
__global__ void reorder_whh(const float* __restrict__ src, u16* __restrict__ dst, int d) {
  int r = blockIdx.x;                 // 0..8191
  int layer = r >> 12, row = r & 4095;
  int g = row >> 10, j = row & 1023;
  int jblk = j >> 4, jl = j & 15;
  size_t drow = ((size_t)(d * 2 + layer) * 64 + jblk) * 64 + g * 16 + jl;
  float4 v = ((const float4*)(src + (size_t)r * KD))[threadIdx.x];
  ushort4 o;
  o.x = f2bf(v.x); o.y = f2bf(v.y); o.z = f2bf(v.z); o.w = f2bf(v.w);
  ((ushort4*)(dst + drow * KD))[threadIdx.x] = o;
}

// -------- fused persistent 2-layer bidirectional LSTM (ONE dispatch) ------
// 256 blocks x 512 thr, 1 block/CU (144 KB LDS). Block: layer = bid>>7,
// dir d = bid&1, jblk = (bid>>1)&63 -> 16 h-dims, all 4 gates. Wave wv:
// gate mt = wv>>1, K-half kh = wv&1. Both weight sets pinned in VGPRs
// (64 regs W_ih + 64 regs W_hh per lane). NO precomputed xg, NO GEMMs:
// each step accumulates x-path MFMA + recurrent MFMA into the same fp32 acc.
//
// Pipelining: layer 1 runs concurrently, one step behind layer 0, consuming
// h0 trajectory slots as layer 0 publishes them (write-once slots -> layer 0
// free-runs, no back-pressure; deadlock-free by induction).
//
// h exchange (proven in r2/r4): producer sc1 stores -> vmcnt(0) -> syncD ->
// tid0 tree RMW (8 subs + root) per (layer,dir); consumer tid0 spins on
// root(s) at step start, then sc1 MALL loads. Layer-1 additionally requires
// layer-0's root >= 8(t+1) before staging h0(tt).
// Layer-0's x staging uses PLAIN cached loads: xbf is replay-deterministic
// (pure function of input), so stale cache lines are value-identical.
__global__ __launch_bounds__(PTHR, 2) void lstm_persist(
    const u16* __restrict__ whh_r,  // [4 wsel][64 jblk][64 rows][1024] bf16
    const u16* __restrict__ wih_r,  // same layout
    const u16* __restrict__ xbf,    // [8192][1024] bf16 (t-major rows)
    u16*       __restrict__ h0t,    // [2d][8192][1024] bf16 layer-0 trajectory
    u16*       __restrict__ h1t,    // [2d][8192][1024] bf16 layer-1 trajectory
    float*     __restrict__ dout,
    unsigned*  __restrict__ cntb)   // zeroed; region (layer*2+d)*512: root 0, subs 16*(1+s)
{
  const int tid = threadIdx.x;
  const int lane = tid & 63;
  const int wv  = tid >> 6;
  const int mt = wv >> 1, kh = wv & 1;
  const int bid = blockIdx.x;
  const int layer = bid >> 7;
  const int d = bid & 1, jblk = (bid >> 1) & 63;
  const int j0 = jblk * 16;
  const int fr = lane & 15, quad = lane >> 4;
  unsigned* cnt   = cntb + (size_t)(layer * 2 + d) * 512;
  unsigned* cntbl = cntb + (size_t)d * 512;        // layer-0 region (below)

  __builtin_amdgcn_fence(__ATOMIC_ACQUIRE, "agent");   // once: drop stale lines

  // 144 KB LDS: lX (below-layer input, 64 KB) + lH (own h(prev), 64 KB),
  // both [32 rows(b)][128 chunks(16B)] with phys chunk = c ^ (row&7);
  // lAcc: separate 16 KB gate-partial exchange [4 mt][2 kh][32 b][16 j].
  __shared__ __align__(16) uint32_t lX[32 * 512];
  __shared__ __align__(16) uint32_t lH[32 * 512];
  __shared__ __align__(16) float lAcc[4096];

  u16*       hme = (layer ? h1t : h0t) + (size_t)d * MROWS * HD;  // own trajectory
  const u16* hbl = h0t + (size_t)d * MROWS * HD;                  // layer-1 lX source

  // ---- one-time weight fragment loads, pinned in VGPRs (128 total) ----
  u4_t wih[16], whh[16];
  {
    const size_t rb = ((size_t)((d * 2 + layer) * 64 + jblk) * 64 + mt * 16 + fr) * KD
                    + kh * 512 + quad * 8;
    #pragma unroll
    for (int ks = 0; ks < 16; ks++) wih[ks] = *(const u4_t*)(wih_r + rb + ks * 32);
    #pragma unroll
    for (int ks = 0; ks < 16; ks++) whh[ks] = *(const u4_t*)(whh_r + rb + ks * 32);
    #pragma unroll
    for (int ks = 0; ks < 16; ks++) {
      asm volatile("" : "+v"(wih[ks]));
      asm volatile("" : "+v"(whh[ks]));   // stop load sinking
    }
  }

  const int b_ = tid >> 3, jp = tid & 7;   // cell phase: tid<256 -> (batch, j-pair)
  float cr0 = 0.0f, cr1 = 0.0f;

  for (int t = 0; t < SEQ; t++) {
    const int tt = d ? (SEQ - 1 - t) : t;

    // ---- start-of-step wait: own layer step t-1 done; below layer step t done ----
    if (tid == 0) {
      const unsigned go = 8u * (unsigned)t;
      const unsigned gb = 8u * (unsigned)(t + 1);
      long spins = 0;
      for (;;) {
        bool ok = (__hip_atomic_load(&cnt[0], __ATOMIC_RELAXED, __HIP_MEMORY_SCOPE_AGENT) >= go);
        if (ok && layer)
          ok = (__hip_atomic_load(&cntbl[0], __ATOMIC_RELAXED, __HIP_MEMORY_SCOPE_AGENT) >= gb);
        if (ok) break;
        if (++spins > (1L << 22)) break;   // safety escape (deadlock only)
      }
    }
    __syncthreads();                       // S
    asm volatile("" ::: "memory");         // keep staging below the wait

    // ---- staging: waves 0-3 -> lX (below input), waves 4-7 -> lH (own h) ----
    if (wv < 4) {
      if (layer) {
        // lX = h0(tt): agent-coherent 8B loads (MALL-served), rows [wv*8,wv*8+8)
        const unsigned long long* s8 = (const unsigned long long*)(hbl + (size_t)tt * BSZ * HD);
        #pragma unroll
        for (int hf = 0; hf < 2; hf++) {
          unsigned long long hv2[16];
          #pragma unroll
          for (int k = 0; k < 8; k++) {
            int kk = hf * 8 + k, row = wv * 8 + (kk >> 1), c = (kk & 1) * 64 + lane;
            size_t ci = ((size_t)row * 128 + c) * 2;
            hv2[2 * k]     = __hip_atomic_load(s8 + ci,     __ATOMIC_RELAXED, __HIP_MEMORY_SCOPE_AGENT);
            hv2[2 * k + 1] = __hip_atomic_load(s8 + ci + 1, __ATOMIC_RELAXED, __HIP_MEMORY_SCOPE_AGENT);
          }
          #pragma unroll
          for (int k = 0; k < 8; k++) {
            int kk = hf * 8 + k, row = wv * 8 + (kk >> 1), c = (kk & 1) * 64 + lane;
            int pc = c ^ (row & 7);
            uint2 lo = __builtin_bit_cast(uint2, hv2[2 * k]);
            uint2 hi = __builtin_bit_cast(uint2, hv2[2 * k + 1]);
            u4_t v; v.x = lo.x; v.y = lo.y; v.z = hi.x; v.w = hi.y;
            *(u4_t*)&lX[row * 512 + pc * 4] = v;
          }
        }
      } else if (t == 0) {
        // lX = x(tt0): plain cached 16B loads (deterministic data)
        const u16* xs = xbf + (size_t)(tt * BSZ) * KD;
        #pragma unroll
        for (int k = 0; k < 16; k++) {
          int row = wv * 8 + (k >> 1), c = (k & 1) * 64 + lane, pc = c ^ (row & 7);
          u4_t v = *(const u4_t*)(xs + (size_t)row * KD + c * 8);
          *(u4_t*)&lX[row * 512 + pc * 4] = v;
        }
      }       // t>0 layer-0: lX(t) was prefetched at tail of step t-1
    } else if (t > 0) {
      // lH = own h(prev): rows [q*8,q*8+8), MALL loads
      const int q = wv - 4;
      const int ttp = d ? (tt + 1) : (tt - 1);
      const unsigned long long* s8 = (const unsigned long long*)(hme + (size_t)ttp * BSZ * HD);
      #pragma unroll
      for (int hf = 0; hf < 2; hf++) {
        unsigned long long hv2[16];
        #pragma unroll
        for (int k = 0; k < 8; k++) {
          int kk = hf * 8 + k, row = q * 8 + (kk >> 1), c = (kk & 1) * 64 + lane;
          size_t ci = ((size_t)row * 128 + c) * 2;
          hv2[2 * k]     = __hip_atomic_load(s8 + ci,     __ATOMIC_RELAXED, __HIP_MEMORY_SCOPE_AGENT);
          hv2[2 * k + 1] = __hip_atomic_load(s8 + ci + 1, __ATOMIC_RELAXED, __HIP_MEMORY_SCOPE_AGENT);
        }
        #pragma unroll
        for (int k = 0; k < 8; k++) {
          int kk = hf * 8 + k, row = q * 8 + (kk >> 1), c = (kk & 1) * 64 + lane;
          int pc = c ^ (row & 7);
          uint2 lo = __builtin_bit_cast(uint2, hv2[2 * k]);
          uint2 hi = __builtin_bit_cast(uint2, hv2[2 * k + 1]);
          u4_t v; v.x = lo.x; v.y = lo.y; v.z = hi.x; v.w = hi.y;
          *(u4_t*)&lH[row * 512 + pc * 4] = v;
        }
      }
    }
    __syncthreads();                       // A: lX + lH staged

    // ---- MFMA: x-path always, recurrent path for t>0; same fp32 acc ----
    f4_t acc0 = {}, acc1 = {};
    #pragma unroll
    for (int ks = 0; ks < 16; ks++) {
      int cbase = ((kh * 64 + ks * 4 + quad) ^ (fr & 7)) << 2;   // (fr+16)&7==fr&7
      bf8_t a0 = *(const bf8_t*)&lX[fr * 512 + cbase];
      bf8_t a1 = *(const bf8_t*)&lX[(fr + 16) * 512 + cbase];
      bf8_t wb = __builtin_bit_cast(bf8_t, wih[ks]);
      acc0 = __builtin_amdgcn_mfma_f32_16x16x32_bf16(a0, wb, acc0, 0, 0, 0);
      acc1 = __builtin_amdgcn_mfma_f32_16x16x32_bf16(a1, wb, acc1, 0, 0, 0);
    }
    if (t > 0) {
      #pragma unroll
      for (int ks = 0; ks < 16; ks++) {
        int cbase = ((kh * 64 + ks * 4 + quad) ^ (fr & 7)) << 2;
        bf8_t a0 = *(const bf8_t*)&lH[fr * 512 + cbase];
        bf8_t a1 = *(const bf8_t*)&lH[(fr + 16) * 512 + cbase];
        bf8_t wb = __builtin_bit_cast(bf8_t, whh[ks]);
        acc0 = __builtin_amdgcn_mfma_f32_16x16x32_bf16(a0, wb, acc0, 0, 0, 0);
        acc1 = __builtin_amdgcn_mfma_f32_16x16x32_bf16(a1, wb, acc1, 0, 0, 0);
      }
    }
    // D layout: col=lane&15 (j), row=(lane>>4)*4+r (batch)
    #pragma unroll
    for (int r = 0; r < 4; r++) {
      lAcc[((mt * 2 + kh) * 32 + quad * 4 + r) * 16 + fr]      = acc0[r];
      lAcc[((mt * 2 + kh) * 32 + 16 + quad * 4 + r) * 16 + fr] = acc1[r];
    }
    __syncthreads();                       // BC: lAcc ready

    // ---- cell update: 256 threads x 2 adjacent j each ----
    if (tid < 256) {
      float vg0[4], vg1[4];
      #pragma unroll
      for (int g = 0; g < 4; g++) {
        float2 p0 = *(const float2*)&lAcc[((g * 2 + 0) * 32 + b_) * 16 + 2 * jp];
        float2 p1 = *(const float2*)&lAcc[((g * 2 + 1) * 32 + b_) * 16 + 2 * jp];
        vg0[g] = p0.x + p1.x;
        vg1[g] = p0.y + p1.y;
      }
      float i0 = sigm(vg0[0]), f0 = sigm(vg0[1]), g0 = tanh_f(vg0[2]), o0 = sigm(vg0[3]);
      float i1 = sigm(vg1[0]), f1 = sigm(vg1[1]), g1 = tanh_f(vg1[2]), o1 = sigm(vg1[3]);
      cr0 = f0 * cr0 + i0 * g0;
      cr1 = f1 * cr1 + i1 * g1;
      float hn0 = o0 * tanh_f(cr0), hn1 = o1 * tanh_f(cr1);
      uint32_t hnp = ((uint32_t)f2bf(hn1) << 16) | (uint32_t)f2bf(hn0);

      // own trajectory store (device-coherent write-through, performed at MALL)
      size_t hq = (((size_t)tt * BSZ + b_) * HD + j0 + 2 * jp) >> 1;
      __hip_atomic_store((uint32_t*)hme + hq, hnp, __ATOMIC_RELAXED, __HIP_MEMORY_SCOPE_AGENT);

      if (layer == 1) {
        float2 o2 = make_float2(hn0, hn1);
        *(float2*)&dout[((size_t)tt * BSZ + b_) * (2 * HD) + (size_t)d * HD + j0 + 2 * jp] = o2;
      }
      // h_last/c_last: fwd at final step; bwd at its FIRST step (torch quirk)
      if ((d == 0 && t == SEQ - 1) || (d == 1 && t == 0)) {
        size_t hoff = (size_t)MROWS * 2 * HD + ((size_t)layer * BSZ + b_) * (2 * HD)
                    + (size_t)d * HD + j0 + 2 * jp;
        dout[hoff] = hn0;  dout[hoff + 1] = hn1;
        dout[hoff + (size_t)2 * BSZ * 2 * HD]     = cr0;
        dout[hoff + (size_t)2 * BSZ * 2 * HD + 1] = cr1;
      }
      // drain own sc1 stores to MALL before syncD (signal comes after syncD)
      asm volatile("s_waitcnt vmcnt(0)" ::: "memory");
    }

    // ---- layer-0 tail prefetch: stage lX(t+1) from static xbf (cached) ----
    // Safe: all lX MFMA reads of step t completed before syncBC.
    if (!layer && wv < 4 && t + 1 < SEQ) {
      const int ttn = d ? (SEQ - 2 - t) : (t + 1);
      const u16* xs = xbf + (size_t)(ttn * BSZ) * KD;
      #pragma unroll
      for (int k = 0; k < 16; k++) {
        int row = wv * 8 + (k >> 1), c = (k & 1) * 64 + lane, pc = c ^ (row & 7);
        u4_t v = *(const u4_t*)(xs + (size_t)row * KD + c * 8);
        *(u4_t*)&lX[row * 512 + pc * 4] = v;
      }
    }

    __syncthreads();                       // D: all cell stores drained
    if (tid == 0) {
      const unsigned sub = (unsigned)(jblk & 7);
      unsigned old = __hip_atomic_fetch_add(&cnt[16 * (1 + sub)], 1u,
                                            __ATOMIC_RELAXED, __HIP_MEMORY_SCOPE_AGENT);
      if (old + 1u == 8u * (unsigned)(t + 1))
        __hip_atomic_fetch_add(&cnt[0], 1u, __ATOMIC_RELAXED, __HIP_MEMORY_SCOPE_AGENT);
    }
  }
}

// -------------------------------------------------------------------------
extern "C" void kernel_launch(void* const* d_in, const int* in_sizes, int n_in,
                              void* d_out, int out_size, void* d_ws, size_t ws_size,
                              hipStream_t stream) {
  const float* x    = (const float*)d_in[0];
  const float* wihf = (const float*)d_in[1];
  const float* whhf = (const float*)d_in[2];
  const float* wihb = (const float*)d_in[3];
  const float* whhb = (const float*)d_in[4];
  float* out = (float*)d_out;

  const size_t NE = (size_t)MROWS * KD;   // 8.4M elems
  u16* ws   = (u16*)d_ws;
  u16* xbf  = ws;                         // [8192][1024] bf16, 16 MB
  u16* whhr = xbf + NE;                   // [4][64][64][1024] bf16, 32 MB
  u16* wihr = whhr + 2 * NE;              // [4][64][64][1024] bf16, 32 MB
  u16* h0   = wihr + 2 * NE;              // [2d][8192][1024] bf16, 32 MB
  u16* h1   = h0 + 2 * NE;                // [2d][8192][1024] bf16, 32 MB
  unsigned* cnt = (unsigned*)(h1 + 2 * NE);  // 4 regions x 512 words

  const int n4 = (int)(NE / 4);
  cvt_f32_bf16<<<n4 / 256, 256, 0, stream>>>(x, xbf, n4);
  reorder_whh<<<2 * GD, 256, 0, stream>>>(whhf, whhr, 0);
  reorder_whh<<<2 * GD, 256, 0, stream>>>(whhb, whhr, 1);
  reorder_whh<<<2 * GD, 256, 0, stream>>>(wihf, wihr, 0);
  reorder_whh<<<2 * GD, 256, 0, stream>>>(wihb, wihr, 1);

  hipMemsetAsync(cnt, 0, 4 * 512 * sizeof(unsigned), stream);

  // single fused dispatch: both layers, both directions, wavefront-pipelined
  lstm_persist<<<PBLK, PTHR, 0, stream>>>(whhr, wihr, xbf, h0, h1, out, cnt);
}